// Round 8
// baseline (1598.727 us; speedup 1.0000x reference)
//
#include <hip/hip_runtime.h>
#include <hip/hip_bf16.h>

// Attention: B=4,H=16,S=2048,D=64. Inputs fp32 Q,K,V [B,H,S,D], mask int32 [B,1,S,S].
// Outputs: out [B,H,S,D] then p_attn [B,H,S,S], fp32, concatenated in d_out.
// Strategy: bf16 MFMA for both GEMMs. Pre-pass (read-once sources loaded
// nontemporal): Q -> bf16 PRE-SCALED by 1/sqrt(d)*log2(e), K -> bf16 (one fused
// launch), V -> bf16 transposed per head (Vt[d][k]), mask -> 1-bit packed
// (64MiB -> 2MiB). Main kernel: one block per (bh, 16 q-rows), XCD-chunk
// swizzled; scores in 32 C-fragments per wave (wave owns 512 keys); packed mask
// prefetched to registers before QK^T; softmax: wave-local max -> exp2 ->
// wave-local sum, ONE LDS exchange of (max,sum) with exact per-wave rescale;
// normalized P 4x4 lane-transposed -> p_attn as nontemporal dwordx4 + bf16 LDS
// copy; pre-PV barrier waits lgkmcnt ONLY (p-stores drain in background,
// overlapped with PV) + sched_barrier fence; PV uses 4 independent MFMA chains.
// Workspace: 48 MiB bf16 bufs + 2 MiB mask bits = 50 MiB of d_ws.
// VGPR audit: peak live ~220 (acc 128 + mask 64 + q 8 + addr/temps) < 256 cap
// from __launch_bounds__(256,2) -> no spill expected. Do not add register load.

#define SDIM 2048
#define DDIM 64
#define NB 4
#define NH 16
#define BHN 64
#define TQ 16
#define OUT_ELEMS (BHN * SDIM * DDIM)   // 8388608

typedef float f32x4 __attribute__((ext_vector_type(4)));
typedef __bf16 bf16x8 __attribute__((ext_vector_type(8)));
typedef __bf16 bf16x4 __attribute__((ext_vector_type(4)));
typedef __bf16 bf16;

// Fused Q+K convert: blocks [0, n8/256) handle Q (scaled), the rest handle K.
__global__ void cvt_qk_kernel(const float* __restrict__ q, const float* __restrict__ k,
                              bf16* __restrict__ Qb, bf16* __restrict__ Kb,
                              int n8, float qscale) {
    int i = blockIdx.x * blockDim.x + threadIdx.x;
    const float* src;
    bf16* dst;
    float scale;
    if (i < n8) {
        src = q; dst = Qb; scale = qscale;
    } else {
        src = k; dst = Kb; scale = 1.0f; i -= n8;
    }
    const f32x4* s4 = (const f32x4*)src;
    f32x4 a = __builtin_nontemporal_load(s4 + 2 * i);
    f32x4 c = __builtin_nontemporal_load(s4 + 2 * i + 1);
    bf16x8 o;
    o[0] = (bf16)(a[0] * scale); o[1] = (bf16)(a[1] * scale);
    o[2] = (bf16)(a[2] * scale); o[3] = (bf16)(a[3] * scale);
    o[4] = (bf16)(c[0] * scale); o[5] = (bf16)(c[1] * scale);
    o[6] = (bf16)(c[2] * scale); o[7] = (bf16)(c[3] * scale);
    *(bf16x8*)(dst + 8 * (size_t)i) = o;
}

// V [bh][k][d] fp32 -> Vt [bh][d][k] bf16. Grid: BHN * (SDIM/64), block 256.
__global__ void transpose_v_kernel(const float* __restrict__ v, bf16* __restrict__ vt) {
    int bh = blockIdx.x >> 5;          // SDIM/64 = 32 tiles
    int k0 = (blockIdx.x & 31) * 64;
    __shared__ bf16 tile[64][72];      // [d][k_local], padded
    int t = threadIdx.x;
    int r = t >> 4;                    // 0..15
    int c4 = (t & 15) * 4;             // 0..60
    const float* vb = v + (size_t)bh * SDIM * DDIM;
#pragma unroll
    for (int i = 0; i < 4; i++) {
        int row = r + 16 * i;
        f32x4 x = __builtin_nontemporal_load(
            (const f32x4*)(vb + (size_t)(k0 + row) * DDIM + c4));
        tile[c4 + 0][row] = (bf16)x[0];
        tile[c4 + 1][row] = (bf16)x[1];
        tile[c4 + 2][row] = (bf16)x[2];
        tile[c4 + 3][row] = (bf16)x[3];
    }
    __syncthreads();
    bf16* vtb = vt + (size_t)bh * DDIM * SDIM;
    int drow = t >> 2;                 // 0..63
    int seg = (t & 3) * 16;            // 16 bf16 = 32B per thread
    uint4 u0 = *(const uint4*)&tile[drow][seg];
    uint4 u1 = *(const uint4*)&tile[drow][seg + 8];
    *(uint4*)(vtb + (size_t)drow * SDIM + k0 + seg) = u0;
    *(uint4*)(vtb + (size_t)drow * SDIM + k0 + seg + 8) = u1;
}

// mask int32 [B*S*S] -> bit-packed [B][S][S/32]. bit=1 means masked (-MAX_VAL).
// One int per thread, wave ballot, lanes 0/32 write 32 bits each. Fully coalesced.
__global__ void pack_mask_kernel(const int* __restrict__ src, unsigned* __restrict__ dst) {
    int i = blockIdx.x * blockDim.x + threadIdx.x;
    int mv = __builtin_nontemporal_load(src + i);
    unsigned long long bal = __ballot(mv == 1);
    int l = threadIdx.x & 63;
    if (l == 0) dst[i >> 5] = (unsigned)bal;
    else if (l == 32) dst[i >> 5] = (unsigned)(bal >> 32);
}

__launch_bounds__(256, 2)
__global__ void attn_kernel(const bf16* __restrict__ Qb, const bf16* __restrict__ Kb,
                            const bf16* __restrict__ Vtb, const unsigned* __restrict__ mbits,
                            float* __restrict__ out, float* __restrict__ p_out) {
    // Bijective XCD-chunk swizzle: grid 8192 = 8 XCD x 1024; each XCD walks
    // 8 consecutive bh sequentially -> K/Vt/mask stay hot in its private L2.
    const int bid0 = blockIdx.x;
    const int bid = (bid0 & 7) * 1024 + (bid0 >> 3);
    const int qt = bid & 127;          // q-tile within head
    const int bh = bid >> 7;           // 0..63
    const int b  = bh >> 4;            // batch (H=16)
    const int t = threadIdx.x;
    const int w = t >> 6;              // wave 0..3
    const int lane = t & 63;
    const int quad = lane >> 4;
    const int l15 = lane & 15;

    __shared__ bf16 pb[TQ * 2056];     // P tile bf16, padded stride (+16B/row)
    __shared__ float redmax[4][16];
    __shared__ float redsum[4][16];

    // ---- Q A-fragments (Q pre-scaled by 1/sqrt(d)*log2e in prepass) ----
    const int qrow = qt * TQ + l15;
    const bf16* qbase = Qb + ((size_t)bh * SDIM + qrow) * DDIM + 8 * quad;
    bf16x8 aq0 = *(const bf16x8*)(qbase);        // d = 0..31 slice
    bf16x8 aq1 = *(const bf16x8*)(qbase + 32);   // d = 32..63 slice

    // ---- prefetch packed mask rows into registers (latency hidden by QK^T) ----
    // Row q = qt*16 + quad*4 + r needs dwords [w*16, w*16+16) of its 64-dword row.
    const unsigned* mrow = mbits + (size_t)b * SDIM * 64
                         + (size_t)(qt * TQ + quad * 4) * 64 + w * 16;
    uint4 mw[4][4];
#pragma unroll
    for (int r = 0; r < 4; r++)
#pragma unroll
        for (int g = 0; g < 4; g++)
            mw[r][g] = *(const uint4*)(mrow + r * 64 + g * 4);

    // ---- QK^T: wave w owns keys [512w, 512w+512) as 32 16-key tiles ----
    f32x4 acc[32];
    const bf16* kbase = Kb + ((size_t)bh * SDIM + w * 512 + l15) * DDIM + 8 * quad;
#pragma unroll
    for (int kt = 0; kt < 32; kt++) {
        const bf16* kp = kbase + (size_t)kt * 16 * DDIM;
        bf16x8 b0 = *(const bf16x8*)(kp);
        bf16x8 b1 = *(const bf16x8*)(kp + 32);
        f32x4 c = {0.f, 0.f, 0.f, 0.f};
        c = __builtin_amdgcn_mfma_f32_16x16x32_bf16(aq0, b0, c, 0, 0, 0);
        c = __builtin_amdgcn_mfma_f32_16x16x32_bf16(aq1, b1, c, 0, 0, 0);
        acc[kt] = c;
    }

    // ---- bit-mask select + wave-local row max (scores already log2-domain) ----
    // C layout: row = 4*quad+r, col = l15 (+16*kt). Bit for col kt*16+l15 lives in
    // dword kt>>1, bit (kt&1)*16 + l15. All indices compile-time constant.
    const float MASKED = -1.4426950e8f;          // -MAX_VAL * log2(e)
    float mx[4] = {-3e38f, -3e38f, -3e38f, -3e38f};
#pragma unroll
    for (int kt = 0; kt < 32; kt++) {
        const int g = kt >> 3;
        const int sel = (kt >> 1) & 3;
#pragma unroll
        for (int r = 0; r < 4; r++) {
            const uint4 u = mw[r][g];
            unsigned dw = sel == 0 ? u.x : sel == 1 ? u.y : sel == 2 ? u.z : u.w;
            unsigned bits = dw >> (((kt & 1) << 4) + l15);
            float s = (bits & 1u) ? MASKED : acc[kt][r];
            acc[kt][r] = s;
            mx[r] = fmaxf(mx[r], s);
        }
    }
#pragma unroll
    for (int off = 1; off < 16; off <<= 1) {
#pragma unroll
        for (int r = 0; r < 4; r++)
            mx[r] = fmaxf(mx[r], __shfl_xor(mx[r], off, 64));
    }
    // mx[r] is now this wave's local max for row quad*4+r.

    // ---- exp2 with WAVE-LOCAL max + wave-local row sum ----
    float sm[4] = {0.f, 0.f, 0.f, 0.f};
#pragma unroll
    for (int kt = 0; kt < 32; kt++) {
#pragma unroll
        for (int r = 0; r < 4; r++) {
            float e = __builtin_amdgcn_exp2f(acc[kt][r] - mx[r]);
            acc[kt][r] = e;
            sm[r] += e;
        }
    }
#pragma unroll
    for (int off = 1; off < 16; off <<= 1) {
#pragma unroll
        for (int r = 0; r < 4; r++)
            sm[r] += __shfl_xor(sm[r], off, 64);
    }

    // ---- ONE cross-wave exchange: (mx_w, sum_w) -> exact global softmax ----
    // sum_g = sum_{w'} sum_{w'} * 2^(mx_{w'} - mx_g); row scale = 2^(mx_w - mx_g)/sum_g.
    // exp2(s-m_w)*2^(m_w-m_g)/sum_g == exp2(s-m_g)/sum_g exactly (real arith).
    // Fully-masked rows: all mx_w = MASKED, e=1, sum_g = 2048 -> uniform (matches ref).
    if (l15 == 0) {
#pragma unroll
        for (int r = 0; r < 4; r++) {
            redmax[w][quad * 4 + r] = mx[r];
            redsum[w][quad * 4 + r] = sm[r];
        }
    }
    __syncthreads();
    float rs[4];
#pragma unroll
    for (int r = 0; r < 4; r++) {
        const int row = quad * 4 + r;
        float m0 = redmax[0][row], m1 = redmax[1][row];
        float m2 = redmax[2][row], m3 = redmax[3][row];
        float mg = fmaxf(fmaxf(m0, m1), fmaxf(m2, m3));
        float stot = redsum[0][row] * __builtin_amdgcn_exp2f(m0 - mg)
                   + redsum[1][row] * __builtin_amdgcn_exp2f(m1 - mg)
                   + redsum[2][row] * __builtin_amdgcn_exp2f(m2 - mg)
                   + redsum[3][row] * __builtin_amdgcn_exp2f(m3 - mg);
        rs[r] = __builtin_amdgcn_exp2f(mx[r] - mg) / stot;
    }

    // ---- normalize + 4x4 lane transpose -> vectorized p_attn + LDS P ----
    // Lanes j=0..3 within each aligned 4-lane group hold rows quad*4+0..3 of cols
    // c4+j; after the butterfly, lane j holds row quad*4+j, cols c4..c4+3.
    // p_attn goes out as nontemporal dwordx4; bf16 LDS copy is one ds_write_b64/kt.
    const int j  = l15 & 3;
    const int c4 = l15 & 12;
    float* prow4 = p_out + (size_t)bh * SDIM * SDIM
                 + (size_t)(qt * TQ + quad * 4 + j) * SDIM + w * 512 + c4;
    bf16* pbrow = pb + (size_t)(quad * 4 + j) * 2056 + w * 512 + c4;
#pragma unroll
    for (int kt = 0; kt < 32; kt++) {
        float v0 = acc[kt][0] * rs[0];
        float v1 = acc[kt][1] * rs[1];
        float v2 = acc[kt][2] * rs[2];
        float v3 = acc[kt][3] * rs[3];
        // phase 1 (xor 1): lanes j&1==0 exchange v1,v3; lanes j&1==1 exchange v0,v2
        float a  = (j & 1) ? v0 : v1;
        float bt = (j & 1) ? v2 : v3;
        a  = __shfl_xor(a, 1, 64);
        bt = __shfl_xor(bt, 1, 64);
        float nv0 = (j & 1) ? a  : v0;
        float nv1 = (j & 1) ? v1 : a;
        float nv2 = (j & 1) ? bt : v2;
        float nv3 = (j & 1) ? v3 : bt;
        // phase 2 (xor 2): lanes j&2==0 exchange nv2,nv3; lanes j&2 exchange nv0,nv1
        a  = (j & 2) ? nv0 : nv2;
        bt = (j & 2) ? nv1 : nv3;
        a  = __shfl_xor(a, 2, 64);
        bt = __shfl_xor(bt, 2, 64);
        v0 = (j & 2) ? a   : nv0;
        v1 = (j & 2) ? bt  : nv1;
        v2 = (j & 2) ? nv2 : a;
        v3 = (j & 2) ? nv3 : bt;
        f32x4 pv = {v0, v1, v2, v3};
        __builtin_nontemporal_store(pv, (f32x4*)(prow4 + kt * 16));
        bf16x4 ph = {(bf16)v0, (bf16)v1, (bf16)v2, (bf16)v3};
        *(bf16x4*)(pbrow + kt * 16) = ph;
    }

    // ---- barrier that does NOT drain the p-store queue ----
    // Only LDS ordering is needed for the P tile: lgkmcnt(0) covers the ds_writes;
    // outstanding global nt-stores (vmcnt) keep draining in the background,
    // overlapped with PV's MFMAs. sched_barrier(0) fences compiler code motion
    // across the inline-asm wait (rule #18 hardening).
    asm volatile("s_waitcnt lgkmcnt(0)" ::: "memory");
    __builtin_amdgcn_s_barrier();
    __builtin_amdgcn_sched_barrier(0);

    // ---- PV: wave w computes out cols [16w, 16w+16) over all 2048 keys ----
    // 4 independent accumulator chains break the serial MFMA dependency
    // (64-deep chain -> 4 x 16-deep) so PV runs at issue rate, not latency.
    f32x4 o0 = {0.f, 0.f, 0.f, 0.f}, o1 = o0, o2 = o0, o3 = o0;
    const bf16* vbase = Vtb + ((size_t)bh * DDIM + w * 16 + l15) * SDIM + 8 * quad;
    const bf16* pbase = pb + l15 * 2056 + 8 * quad;
    __builtin_amdgcn_s_setprio(1);
#pragma unroll
    for (int ks = 0; ks < 64; ks += 4) {
        bf16x8 a0 = *(const bf16x8*)(pbase + 32 * ks);
        bf16x8 a1 = *(const bf16x8*)(pbase + 32 * (ks + 1));
        bf16x8 a2 = *(const bf16x8*)(pbase + 32 * (ks + 2));
        bf16x8 a3 = *(const bf16x8*)(pbase + 32 * (ks + 3));
        bf16x8 w0 = *(const bf16x8*)(vbase + 32 * ks);
        bf16x8 w1 = *(const bf16x8*)(vbase + 32 * (ks + 1));
        bf16x8 w2 = *(const bf16x8*)(vbase + 32 * (ks + 2));
        bf16x8 w3 = *(const bf16x8*)(vbase + 32 * (ks + 3));
        o0 = __builtin_amdgcn_mfma_f32_16x16x32_bf16(a0, w0, o0, 0, 0, 0);
        o1 = __builtin_amdgcn_mfma_f32_16x16x32_bf16(a1, w1, o1, 0, 0, 0);
        o2 = __builtin_amdgcn_mfma_f32_16x16x32_bf16(a2, w2, o2, 0, 0, 0);
        o3 = __builtin_amdgcn_mfma_f32_16x16x32_bf16(a3, w3, o3, 0, 0, 0);
    }
    __builtin_amdgcn_s_setprio(0);
    f32x4 o = (o0 + o1) + (o2 + o3);
    float* orow = out + ((size_t)bh * SDIM + qt * TQ + quad * 4) * DDIM + w * 16 + l15;
#pragma unroll
    for (int r = 0; r < 4; r++)
        __builtin_nontemporal_store(o[r], orow + (size_t)r * DDIM);
}

extern "C" void kernel_launch(void* const* d_in, const int* in_sizes, int n_in,
                              void* d_out, int out_size, void* d_ws, size_t ws_size,
                              hipStream_t stream) {
    const float* q = (const float*)d_in[0];
    const float* k = (const float*)d_in[1];
    const float* v = (const float*)d_in[2];
    const int* mask = (const int*)d_in[3];
    float* out = (float*)d_out;
    float* p = out + (size_t)OUT_ELEMS;

    bf16* Qb  = (bf16*)d_ws;                          // 16 MB
    bf16* Kb  = Qb + (size_t)BHN * SDIM * DDIM;       // 16 MB
    bf16* Vtb = Kb + (size_t)BHN * SDIM * DDIM;       // 16 MB
    unsigned* Mb = (unsigned*)(Vtb + (size_t)BHN * SDIM * DDIM);  // 2 MB (total 50 MB)

    const float SC = 0.125f * 1.44269504f;            // 1/sqrt(64) * log2(e)
    cvt_qk_kernel<<<8192, 256, 0, stream>>>(q, k, Qb, Kb, OUT_ELEMS / 8, SC);
    transpose_v_kernel<<<BHN * (SDIM / 64), 256, 0, stream>>>(v, Vtb);
    pack_mask_kernel<<<(NB * SDIM * SDIM) / 256, 256, 0, stream>>>(mask, Mb);
    attn_kernel<<<BHN * (SDIM / TQ), 256, 0, stream>>>(Qb, Kb, Vtb, Mb, out, p);
}